// Round 4
// baseline (10938.358 us; speedup 1.0000x reference)
//
#include <hip/hip_runtime.h>
#include <math.h>

typedef unsigned short u16;
typedef unsigned int   u32;
typedef __attribute__((ext_vector_type(8))) short bf16x8;
typedef __attribute__((ext_vector_type(4))) float f32x4;

namespace {
constexpr int B_ = 1024, T_ = 168, H_ = 512, K_ = 8, TAU_ = 24;
}

__device__ __forceinline__ u16 f2bf(float x) {
    u32 u = __float_as_uint(x);
    return (u16)((u + 0x7fffu + ((u >> 16) & 1u)) >> 16);
}
__device__ __forceinline__ float bf2f(u16 b) { return __uint_as_float(((u32)b) << 16); }
__device__ __forceinline__ float sig_(float x) { return 1.0f / (1.0f + expf(-x)); }

__device__ __forceinline__ void gl16(const u16* g, char* l) {
    __builtin_amdgcn_global_load_lds((const __attribute__((address_space(1))) void*)g,
                                     (__attribute__((address_space(3))) void*)l, 16, 0, 0);
}
#define MFMA16 __builtin_amdgcn_mfma_f32_16x16x32_bf16

struct CellA {
    const u16 *Ain, *AinLo; long ldaIn; int ncIn; long KwIn;  // input phase
    const u16 *Wih_h, *Wih_l;
    const u16 *Hh, *Hl;                  // recurrent h (hi/lo) [B,512]
    const u16 *Whh_h, *Whh_l;            // [2048,512]
    const float *bsum;                   // bih+bhh combined [2048]
    float *c;                            // fp32 cell state [B,512]
    u16 *oh, *ol;                        // h out hi/lo
};

// gates = A@Wih^T + H@Whh^T, double-bf16 split (3 MFMA products), LSTM epilogue.
// Tile: 64 rows x 128 wrows (32 j x 4 gates, gate-interleaved), BK=64.
// 4 waves 2x2; dbuf 96KB LDS; counted-vmcnt pipeline; XOR-swizzled tiles.
extern "C" __global__ void __launch_bounds__(256, 1)
cell_kernel(CellA a0, CellA a1, int two)
{
    extern __shared__ char lds[];   // 2 x 48KB: [Ah 8K|Al 8K|Wh 16K|Wl 16K]

    const int id = blockIdx.x;
    int cell, rem;
    if (two) { cell = (id >> 3) & 1; rem = (id & 7) * 32 + (id >> 4); }
    else     { cell = 0;             rem = (id & 7) * 32 + (id >> 3); }
    const CellA& A = cell ? a1 : a0;
    const int row0 = (rem & 15) * 64;
    const int j0   = ((rem >> 4) & 15) * 32;

    const int tid  = threadIdx.x;
    const int wid  = tid >> 6;
    const int lane = tid & 63;
    const int c16  = lane & 15, lq = lane >> 4;
    const int wr   = wid >> 1,  wc = wid & 1;

    // ---------- staging geometry (per thread) ----------
    const int  tr = tid >> 3, sl = tid & 7;
    const long kC = (long)((sl ^ (tr & 7)) << 3);     // pre-swizzled k elem offset
    const long aIn0 = (long)(row0 + tr) * A.ldaIn + kC;
    const long aIn1 = aIn0 + 32 * A.ldaIn;
    const long aR0  = (long)(row0 + tr) * H_ + kC;
    const long aR1  = aR0 + 32 * H_;
    long wg[4], wIn[4], wR[4];
    #pragma unroll
    for (int q = 0; q < 4; ++q) {
        const int r_l = q * 32 + tr;
        wg[q] = (long)(((r_l >> 4) & 3) * H_ + j0 + (r_l >> 6) * 16 + (r_l & 15));
        wIn[q] = wg[q] * A.KwIn + kC;
        wR[q]  = wg[q] * H_     + kC;
    }
    const int NC = A.ncIn + (H_ >> 6);

    auto stageChunk = [&](int ci) {
        char* lb = lds + (ci & 1) * 49152;
        const u16 *Ap, *Alp, *Wp, *Wlp;
        long a0_, a1_, w0_, w1_, w2_, w3_, k0;
        if (ci < A.ncIn) {
            Ap = A.Ain; Alp = A.AinLo; Wp = A.Wih_h; Wlp = A.Wih_l;
            a0_ = aIn0; a1_ = aIn1;
            w0_ = wIn[0]; w1_ = wIn[1]; w2_ = wIn[2]; w3_ = wIn[3];
            k0 = (long)ci << 6;
        } else {
            Ap = A.Hh; Alp = A.Hl; Wp = A.Whh_h; Wlp = A.Whh_l;
            a0_ = aR0; a1_ = aR1;
            w0_ = wR[0]; w1_ = wR[1]; w2_ = wR[2]; w3_ = wR[3];
            k0 = (long)(ci - A.ncIn) << 6;
        }
        gl16(Ap  + a0_ + k0, lb +         tid * 16);
        gl16(Ap  + a1_ + k0, lb + 4096  + tid * 16);
        gl16(Alp + a0_ + k0, lb + 8192  + tid * 16);
        gl16(Alp + a1_ + k0, lb + 12288 + tid * 16);
        gl16(Wp  + w0_ + k0, lb + 16384 + tid * 16);
        gl16(Wp  + w1_ + k0, lb + 20480 + tid * 16);
        gl16(Wp  + w2_ + k0, lb + 24576 + tid * 16);
        gl16(Wp  + w3_ + k0, lb + 28672 + tid * 16);
        gl16(Wlp + w0_ + k0, lb + 32768 + tid * 16);
        gl16(Wlp + w1_ + k0, lb + 36864 + tid * 16);
        gl16(Wlp + w2_ + k0, lb + 40960 + tid * 16);
        gl16(Wlp + w3_ + k0, lb + 45056 + tid * 16);
    };

    // ---------- compute geometry (per lane) ----------
    const int sx = (c16 & 7) << 4;
    const int ab0 = (wr * 32 + c16) * 128;            // m=0 A row base (bytes)
    const int ab1 = (wr * 32 + 16 + c16) * 128;       // m=1
    int wb[4];
    #pragma unroll
    for (int nf = 0; nf < 4; ++nf) wb[nf] = (wc * 64 + nf * 16 + c16) * 128;

    f32x4 acc[4][2];
    #pragma unroll
    for (int nf = 0; nf < 4; ++nf)
        #pragma unroll
        for (int m = 0; m < 2; ++m)
            #pragma unroll
            for (int q = 0; q < 4; ++q) acc[nf][m][q] = 0.f;

    stageChunk(0);
    for (int i = 0; i < NC; ++i) {
        asm volatile("s_waitcnt lgkmcnt(0)" ::: "memory");
        __builtin_amdgcn_s_barrier();                 // done reading buf being overwritten
        if (i + 1 < NC) {
            stageChunk(i + 1);
            asm volatile("s_waitcnt vmcnt(12)" ::: "memory");  // chunk i landed; 12 in flight
        } else {
            asm volatile("s_waitcnt vmcnt(0)" ::: "memory");
        }
        __builtin_amdgcn_sched_barrier(0);
        __builtin_amdgcn_s_barrier();                 // chunk i visible to all waves
        __builtin_amdgcn_sched_barrier(0);

        char* lb = lds + (i & 1) * 49152;
        #pragma unroll
        for (int ks = 0; ks < 2; ++ks) {
            const int kb = (((ks * 4 + lq) << 4) ^ sx);
            bf16x8 ah0 = *(const bf16x8*)(lb + ab0 + kb);
            bf16x8 ah1 = *(const bf16x8*)(lb + ab1 + kb);
            bf16x8 al0 = *(const bf16x8*)(lb + 8192 + ab0 + kb);
            bf16x8 al1 = *(const bf16x8*)(lb + 8192 + ab1 + kb);
            #pragma unroll
            for (int nf = 0; nf < 4; ++nf) {
                bf16x8 wh = *(const bf16x8*)(lb + 16384 + wb[nf] + kb);
                bf16x8 wl = *(const bf16x8*)(lb + 32768 + wb[nf] + kb);
                acc[nf][0] = MFMA16(ah0, wh, acc[nf][0], 0, 0, 0);
                acc[nf][1] = MFMA16(ah1, wh, acc[nf][1], 0, 0, 0);
                acc[nf][0] = MFMA16(ah0, wl, acc[nf][0], 0, 0, 0);
                acc[nf][1] = MFMA16(ah1, wl, acc[nf][1], 0, 0, 0);
                acc[nf][0] = MFMA16(al0, wh, acc[nf][0], 0, 0, 0);
                acc[nf][1] = MFMA16(al1, wh, acc[nf][1], 0, 0, 0);
            }
        }
    }

    // ---------- epilogue: all 4 gates in-lane ----------
    const int j = j0 + wc * 16 + c16;
    float bs[4];
    #pragma unroll
    for (int g = 0; g < 4; ++g) bs[g] = A.bsum[g * H_ + j];
    #pragma unroll
    for (int m = 0; m < 2; ++m)
        #pragma unroll
        for (int r = 0; r < 4; ++r) {
            const int  b    = row0 + wr * 32 + m * 16 + lq * 4 + r;
            const long base = (long)b * H_ + j;
            const float cold = A.c[base];
            const float pi = acc[0][m][r] + bs[0];
            const float pf = acc[1][m][r] + bs[1];
            const float pg = acc[2][m][r] + bs[2];
            const float po = acc[3][m][r] + bs[3];
            const float cn = sig_(pf) * cold + sig_(pi) * tanhf(pg);
            const float hn = sig_(po) * tanhf(cn);
            A.c[base] = cn;
            const u16 hh = f2bf(hn);
            A.oh[base] = hh;
            A.ol[base] = f2bf(hn - bf2f(hh));
        }
}

// x[B][T][32] -> xph[t][B][64] bf16-hi, zero-padded k 32..63
extern "C" __global__ void __launch_bounds__(256)
padx_kernel(const float* __restrict__ x, u16* __restrict__ xph)
{
    int idx = blockIdx.x * 256 + threadIdx.x;       // t*B + b
    int t = idx >> 10, b = idx & 1023;
    if (t >= T_) return;
    const float* src = x + ((long)b * T_ + t) * 32;
    u16* dst = xph + (long)idx * 64;
    #pragma unroll
    for (int q = 0; q < 8; ++q) {
        float4 v = *(const float4*)&src[q * 4];
        ushort4 h;
        h.x = f2bf(v.x); h.y = f2bf(v.y); h.z = f2bf(v.z); h.w = f2bf(v.w);
        *(ushort4*)&dst[q * 4] = h;
    }
    #pragma unroll
    for (int q = 8; q < 16; ++q) *(ushort4*)&dst[q * 4] = make_ushort4(0, 0, 0, 0);
}

// Wih0[2048][32] -> hi/lo [2048][64] zero-padded
extern "C" __global__ void __launch_bounds__(256)
padw_kernel(const float* __restrict__ w, u16* __restrict__ hi, u16* __restrict__ lo)
{
    int idx = blockIdx.x * 256 + threadIdx.x;       // row*16 + k4 (32768)
    int row = idx >> 4, k4 = idx & 15;
    ushort4 hv = make_ushort4(0, 0, 0, 0), lv = hv;
    if (k4 < 8) {
        float4 v = *(const float4*)&w[(long)row * 32 + k4 * 4];
        hv.x = f2bf(v.x); hv.y = f2bf(v.y); hv.z = f2bf(v.z); hv.w = f2bf(v.w);
        lv.x = f2bf(v.x - bf2f(hv.x)); lv.y = f2bf(v.y - bf2f(hv.y));
        lv.z = f2bf(v.z - bf2f(hv.z)); lv.w = f2bf(v.w - bf2f(hv.w));
    }
    *(ushort4*)&hi[(long)row * 64 + k4 * 4] = hv;
    *(ushort4*)&lo[(long)row * 64 + k4 * 4] = lv;
}

// fp32 -> bf16 hi/lo split
extern "C" __global__ void __launch_bounds__(256)
split4(const float* __restrict__ in, u16* __restrict__ hi, u16* __restrict__ lo, int n4)
{
    int i = blockIdx.x * 256 + threadIdx.x;
    if (i < n4) {
        float4 v = ((const float4*)in)[i];
        u16 h0 = f2bf(v.x), h1 = f2bf(v.y), h2 = f2bf(v.z), h3 = f2bf(v.w);
        ushort4 Hv; Hv.x = h0; Hv.y = h1; Hv.z = h2; Hv.w = h3;
        ushort4 Lv;
        Lv.x = f2bf(v.x - bf2f(h0)); Lv.y = f2bf(v.y - bf2f(h1));
        Lv.z = f2bf(v.z - bf2f(h2)); Lv.w = f2bf(v.w - bf2f(h3));
        ((ushort4*)hi)[i] = Hv; ((ushort4*)lo)[i] = Lv;
    }
}

extern "C" __global__ void __launch_bounds__(256)
bias_kernel(const float* a0, const float* b0, const float* a1, const float* b1,
            const float* a2, const float* b2, const float* a3, const float* b3,
            float* out)   // out[4][2048]
{
    int i = blockIdx.x * 256 + threadIdx.x;
    int l = i >> 11, k = i & 2047;
    const float* pa = l == 0 ? a0 : l == 1 ? a1 : l == 2 ? a2 : a3;
    const float* pb = l == 0 ? b0 : l == 1 ? b1 : l == 2 ? b2 : b3;
    out[i] = pa[k] + pb[k];
}

extern "C" __global__ void __launch_bounds__(256)
zero16(uint4* p, int n)
{
    for (int i = blockIdx.x * 256 + threadIdx.x; i < n; i += gridDim.x * 256)
        p[i] = make_uint4(0, 0, 0, 0);
}

// mu / sigma heads for decoder step t
extern "C" __global__ void __launch_bounds__(256)
head_kernel(const u16* __restrict__ hh, const u16* __restrict__ hl,
            const float* __restrict__ W1, const float* __restrict__ b1,
            const float* __restrict__ W2, const float* __restrict__ b2,
            float* __restrict__ out, int t)
{
    int idx = blockIdx.x * 256 + threadIdx.x;       // 0..16383
    int b = idx >> 4, r = idx & 15, k = r & 7, which = r >> 3;
    const float* w  = (which ? W2 : W1) + (long)k * H_;
    const u16*   ph = hh + (long)b * H_;
    const u16*   pl = hl + (long)b * H_;
    float sum = 0.f;
    for (int d = 0; d < H_; d += 8) {
        uint4 uh = *(const uint4*)&ph[d];
        uint4 ul = *(const uint4*)&pl[d];
        float4 w0 = *(const float4*)&w[d];
        float4 w1 = *(const float4*)&w[d + 4];
        sum = fmaf(bf2f((u16)(uh.x & 0xffff)) + bf2f((u16)(ul.x & 0xffff)), w0.x, sum);
        sum = fmaf(bf2f((u16)(uh.x >> 16))    + bf2f((u16)(ul.x >> 16)),    w0.y, sum);
        sum = fmaf(bf2f((u16)(uh.y & 0xffff)) + bf2f((u16)(ul.y & 0xffff)), w0.z, sum);
        sum = fmaf(bf2f((u16)(uh.y >> 16))    + bf2f((u16)(ul.y >> 16)),    w0.w, sum);
        sum = fmaf(bf2f((u16)(uh.z & 0xffff)) + bf2f((u16)(ul.z & 0xffff)), w1.x, sum);
        sum = fmaf(bf2f((u16)(uh.z >> 16))    + bf2f((u16)(ul.z >> 16)),    w1.y, sum);
        sum = fmaf(bf2f((u16)(uh.w & 0xffff)) + bf2f((u16)(ul.w & 0xffff)), w1.z, sum);
        sum = fmaf(bf2f((u16)(uh.w >> 16))    + bf2f((u16)(ul.w >> 16)),    w1.w, sum);
    }
    long o = ((long)b * TAU_ + t) * K_ + k;
    if (which == 0) {
        out[o] = sum + b1[k];
    } else {
        float z  = 2.0f * (sum + b2[k]);
        float sp = fmaxf(z, 0.0f) + log1pf(expf(-fabsf(z)));
        out[(long)B_ * TAU_ * K_ + o] = 0.5f * sp;
    }
}

extern "C" void kernel_launch(void* const* d_in, const int* in_sizes, int n_in,
                              void* d_out, int out_size, void* d_ws, size_t ws_size,
                              hipStream_t stream)
{
    (void)in_sizes; (void)n_in; (void)out_size; (void)ws_size;

    const float* x     = (const float*)d_in[0];
    const float* eWih0 = (const float*)d_in[1];
    const float* eWhh0 = (const float*)d_in[2];
    const float* ebih0 = (const float*)d_in[3];
    const float* ebhh0 = (const float*)d_in[4];
    const float* eWih1 = (const float*)d_in[5];
    const float* eWhh1 = (const float*)d_in[6];
    const float* ebih1 = (const float*)d_in[7];
    const float* ebhh1 = (const float*)d_in[8];
    const float* dWih0 = (const float*)d_in[9];
    const float* dWhh0 = (const float*)d_in[10];
    const float* dbih0 = (const float*)d_in[11];
    const float* dbhh0 = (const float*)d_in[12];
    const float* dWih1 = (const float*)d_in[13];
    const float* dWhh1 = (const float*)d_in[14];
    const float* dbih1 = (const float*)d_in[15];
    const float* dbhh1 = (const float*)d_in[16];
    const float* W1    = (const float*)d_in[17];
    const float* b1    = (const float*)d_in[18];
    const float* W2    = (const float*)d_in[19];
    const float* b2    = (const float*)d_in[20];
    float* out = (float*)d_out;

    (void)hipFuncSetAttribute((const void*)cell_kernel,
                              hipFuncAttributeMaxDynamicSharedMemorySize, 98304);

    char* wsp = (char*)d_ws;
    auto take = [&](size_t n) { void* p = (void*)wsp; wsp += n; return p; };

    u16* xph = (u16*)take((size_t)T_ * B_ * 64 * 2);
    u16* w0h = (u16*)take((size_t)2048 * 64 * 2);
    u16* w0l = (u16*)take((size_t)2048 * 64 * 2);

    const float* wsrc[7] = { eWhh0, eWih1, eWhh1, dWih0, dWhh0, dWih1, dWhh1 };
    u16 *ph[7], *pl[7];
    const size_t WN = (size_t)2048 * 512;
    for (int i = 0; i < 7; ++i) { ph[i] = (u16*)take(WN * 2); pl[i] = (u16*)take(WN * 2); }

    float* bsum = (float*)take((size_t)4 * 2048 * 4);

    const size_t NH = (size_t)B_ * H_;
    char* zstart = wsp;
    u16* zeroA = (u16*)take((size_t)B_ * 64 * 2);
    u16 *h0h[2], *h0l[2], *h1h[2], *h1l[2];
    for (int p = 0; p < 2; ++p) { h0h[p] = (u16*)take(NH * 2); h0l[p] = (u16*)take(NH * 2); }
    for (int p = 0; p < 2; ++p) { h1h[p] = (u16*)take(NH * 2); h1l[p] = (u16*)take(NH * 2); }
    float* c0 = (float*)take(NH * 4);
    float* c1 = (float*)take(NH * 4);
    const size_t zeroBytes = (size_t)(wsp - zstart);

    const dim3 blk(256);

    padx_kernel<<<dim3(T_ * B_ / 256), blk, 0, stream>>>(x, xph);
    padw_kernel<<<dim3(128), blk, 0, stream>>>(eWih0, w0h, w0l);
    for (int i = 0; i < 7; ++i)
        split4<<<dim3((unsigned)(WN / 4 / 256)), blk, 0, stream>>>(wsrc[i], ph[i], pl[i], (int)(WN / 4));
    bias_kernel<<<dim3(32), blk, 0, stream>>>(ebih0, ebhh0, ebih1, ebhh1,
                                              dbih0, dbhh0, dbih1, dbhh1, bsum);
    zero16<<<dim3(1024), blk, 0, stream>>>((uint4*)zstart, (int)(zeroBytes / 16));

    auto mkL0e = [&](int t, int pin, int pout) {
        CellA c;
        c.Ain = xph + (size_t)t * B_ * 64; c.AinLo = zeroA; c.ldaIn = 64; c.ncIn = 1; c.KwIn = 64;
        c.Wih_h = w0h; c.Wih_l = w0l;
        c.Hh = h0h[pin]; c.Hl = h0l[pin];
        c.Whh_h = ph[0]; c.Whh_l = pl[0];
        c.bsum = bsum; c.c = c0;
        c.oh = h0h[pout]; c.ol = h0l[pout];
        return c;
    };
    auto mkL1e = [&](int pa, int pin, int pout) {
        CellA c;
        c.Ain = h0h[pa]; c.AinLo = h0l[pa]; c.ldaIn = H_; c.ncIn = 8; c.KwIn = H_;
        c.Wih_h = ph[1]; c.Wih_l = pl[1];
        c.Hh = h1h[pin]; c.Hl = h1l[pin];
        c.Whh_h = ph[2]; c.Whh_l = pl[2];
        c.bsum = bsum + 2048; c.c = c1;
        c.oh = h1h[pout]; c.ol = h1l[pout];
        return c;
    };
    auto mkL0d = [&](int pa, int pin, int pout) {
        CellA c;
        c.Ain = h1h[pa]; c.AinLo = h1l[pa]; c.ldaIn = H_; c.ncIn = 8; c.KwIn = H_;
        c.Wih_h = ph[3]; c.Wih_l = pl[3];
        c.Hh = h0h[pin]; c.Hl = h0l[pin];
        c.Whh_h = ph[4]; c.Whh_l = pl[4];
        c.bsum = bsum + 4096; c.c = c0;
        c.oh = h0h[pout]; c.ol = h0l[pout];
        return c;
    };
    auto mkL1d = [&](int pa, int pin, int pout) {
        CellA c;
        c.Ain = h0h[pa]; c.AinLo = h0l[pa]; c.ldaIn = H_; c.ncIn = 8; c.KwIn = H_;
        c.Wih_h = ph[5]; c.Wih_l = pl[5];
        c.Hh = h1h[pin]; c.Hl = h1l[pin];
        c.Whh_h = ph[6]; c.Whh_l = pl[6];
        c.bsum = bsum + 6144; c.c = c1;
        c.oh = h1h[pout]; c.ol = h1l[pout];
        return c;
    };

    int p0 = 1, p1 = 1;    // zeros live in buffer 1

    { CellA a = mkL0e(0, p0, p0 ^ 1);
      cell_kernel<<<dim3(256), blk, 98304, stream>>>(a, a, 0); p0 ^= 1; }

    for (int t = 0; t < T_ - 1; ++t) {              // stagger: L1(t) || L0(t+1)
        CellA l1 = mkL1e(p0, p1, p1 ^ 1);
        CellA l0 = mkL0e(t + 1, p0, p0 ^ 1);
        cell_kernel<<<dim3(512), blk, 98304, stream>>>(l1, l0, 1);
        p0 ^= 1; p1 ^= 1;
    }
    { CellA a = mkL1e(p0, p1, p1 ^ 1);
      cell_kernel<<<dim3(256), blk, 98304, stream>>>(a, a, 0); p1 ^= 1; }

    for (int t = 0; t < TAU_; ++t) {
        CellA a = mkL0d(p1, p0, p0 ^ 1);
        cell_kernel<<<dim3(256), blk, 98304, stream>>>(a, a, 0); p0 ^= 1;
        CellA b_ = mkL1d(p0, p1, p1 ^ 1);
        cell_kernel<<<dim3(256), blk, 98304, stream>>>(b_, b_, 0); p1 ^= 1;
        head_kernel<<<dim3(64), blk, 0, stream>>>(h1h[p1], h1l[p1], W1, b1, W2, b2, out, t);
    }
}

// Round 5
// 6759.333 us; speedup vs baseline: 1.6183x; 1.6183x over previous
//
#include <hip/hip_runtime.h>
#include <math.h>

typedef unsigned short u16;
typedef unsigned int   u32;
typedef __attribute__((ext_vector_type(8))) short bf16x8;
typedef __attribute__((ext_vector_type(4))) float f32x4;

namespace {
constexpr int B_ = 1024, T_ = 168, D_ = 32, H_ = 512, K_ = 8, TAU_ = 24;
}

__device__ __forceinline__ u16 f2bf(float x) {
    u32 u = __float_as_uint(x);
    return (u16)((u + 0x7fffu + ((u >> 16) & 1u)) >> 16);
}
__device__ __forceinline__ float bf2f(u16 b) { return __uint_as_float(((u32)b) << 16); }
__device__ __forceinline__ float sig_(float x) { return 1.0f / (1.0f + expf(-x)); }

__device__ __forceinline__ void gl16(const u16* g, void* l) {
    __builtin_amdgcn_global_load_lds((const __attribute__((address_space(1))) void*)g,
                                     (__attribute__((address_space(3))) void*)l, 16, 0, 0);
}
#define MFMA16 __builtin_amdgcn_mfma_f32_16x16x32_bf16

struct CellA {
    const u16 *Ah, *Al; long lda; long Kx;      // input activations (hi/lo bf16)
    const u16 *Wih_h, *Wih_l;                   // [2048, Kx]
    const u16 *Hh, *Hl;                         // recurrent h (hi/lo), [B,512]
    const u16 *Whh_h, *Whh_l;                   // [2048, 512]
    const float *bih, *bhh;
    float *c;                                   // cell state fp32 [B,512]
    u16 *oh, *ol;                               // h output hi/lo
};

// gates = A@Wih^T + H@Whh^T via double-bf16 split (3 products per staged chunk).
// Block tile: 64 rows x 16 j (x4 gates). 2-deep counted-vmcnt pipeline,
// dbuf 64KB LDS, XOR-swizzled tiles (pre-swizzled global src + swizzled read).
extern "C" __global__ void __launch_bounds__(256, 2)
cell_kernel(CellA a0, CellA a1, int nblk)
{
    __shared__ char lds[65536];     // 2 bufs x {Ah 8K | Al 8K | Wh 8K | Wl 8K}

    // bijective XCD-chunked remap
    const int id  = blockIdx.x;
    const int id2 = (id & 7) * (nblk >> 3) + (id >> 3);
    const CellA& A = (id2 < 512) ? a0 : a1;
    const int rem  = id2 & 511;
    const int row0 = (rem & 15) * 64;
    const int j0   = (rem >> 4) * 16;

    const int tid  = threadIdx.x;
    const int wid  = tid >> 6;
    const int lane = tid & 63;
    const int l16  = lane & 15, lq = lane >> 4;
    const int arow = wid * 16 + l16;
    const int swzA = (l16 & 7) << 4;

    // ---- staging per-thread geometry ----
    const int r0   = tid >> 3;
    const int kb64 = (((tid & 7) << 4) ^ ((r0 & 7) << 4));
    const int r32  = tid >> 2;
    const int kb32 = (((tid & 3) << 4) ^ (((r32 & 7) << 4) & 48));

    auto grow = [&](int r) { return (r >> 4) * H_ + j0 + (r & 15); };

    const long recA0 = (long)(row0 + r0) * H_ + (kb64 >> 1);
    const long recA1 = recA0 + 32 * H_;
    const long recW0 = (long)grow(r0) * H_ + (kb64 >> 1);
    const long recW1 = (long)grow(r0 + 32) * H_ + (kb64 >> 1);

    const long ldx = A.lda, Kx = A.Kx;
    const bool smallk = (Kx == 32);
    long inA0, inA1 = 0, inW0, inW1 = 0;
    if (smallk) {
        inA0 = (long)(row0 + r32) * ldx + (kb32 >> 1);
        inW0 = (long)grow(r32) * 32 + (kb32 >> 1);
    } else {
        inA0 = (long)(row0 + r0) * ldx + (kb64 >> 1);
        inA1 = inA0 + 32 * ldx;
        inW0 = (long)grow(r0) * Kx + (kb64 >> 1);
        inW1 = (long)grow(r0 + 32) * Kx + (kb64 >> 1);
    }

    const int ncIn = smallk ? 1 : (int)(Kx >> 6);
    const int NC   = ncIn + (H_ >> 6);

    auto stage64 = [&](char* lb, const u16* Ahp, const u16* Alp,
                       const u16* Whp, const u16* Wlp,
                       long a0_, long a1_, long w0_, long w1_, int k0) {
        gl16(Ahp + a0_ + k0, lb + tid * 16);
        gl16(Ahp + a1_ + k0, lb + 4096  + tid * 16);
        gl16(Alp + a0_ + k0, lb + 8192  + tid * 16);
        gl16(Alp + a1_ + k0, lb + 12288 + tid * 16);
        gl16(Whp + w0_ + k0, lb + 16384 + tid * 16);
        gl16(Whp + w1_ + k0, lb + 20480 + tid * 16);
        gl16(Wlp + w0_ + k0, lb + 24576 + tid * 16);
        gl16(Wlp + w1_ + k0, lb + 28672 + tid * 16);
    };

    // returns # of gl16 issued for this chunk (for counted vmcnt)
    auto stageChunk = [&](int ci) -> int {
        char* lb = lds + ((ci & 1) << 15);
        if (ci < ncIn) {
            if (smallk) {
                gl16(A.Ah + inA0,    lb + tid * 16);
                gl16(A.Al + inA0,    lb + 8192  + tid * 16);
                gl16(A.Wih_h + inW0, lb + 16384 + tid * 16);
                gl16(A.Wih_l + inW0, lb + 24576 + tid * 16);
                return 4;
            }
            stage64(lb, A.Ah, A.Al, A.Wih_h, A.Wih_l,
                    inA0, inA1, inW0, inW1, ci << 6);
            return 8;
        }
        stage64(lb, A.Hh, A.Hl, A.Whh_h, A.Whh_l,
                recA0, recA1, recW0, recW1, (ci - ncIn) << 6);
        return 8;
    };

    f32x4 acc[4];
    #pragma unroll
    for (int g = 0; g < 4; ++g)
        #pragma unroll
        for (int q = 0; q < 4; ++q) acc[g][q] = 0.f;

    // ---- 2-deep pipeline: never drain vmcnt to 0 in the loop ----
    stageChunk(0);
    stageChunk(1);          // NC >= 9 always, so chunk 1 exists
    for (int i = 0; i < NC; ++i) {
        // wait: chunk i landed; chunk i+1's loads (8) may stay in flight
        if (i + 1 < NC) asm volatile("s_waitcnt vmcnt(8)" ::: "memory");
        else            asm volatile("s_waitcnt vmcnt(0)" ::: "memory");
        __builtin_amdgcn_s_barrier();             // chunk i visible to all waves

        char* lb = lds + ((i & 1) << 15);
        if (smallk && i == 0) {
            const int kb = (lq * 16) ^ (swzA & 48);
            bf16x8 ah = *(const bf16x8*)(lb + arow * 64 + kb);
            bf16x8 al = *(const bf16x8*)(lb + 8192 + arow * 64 + kb);
            #pragma unroll
            for (int g = 0; g < 4; ++g) {
                const int wrow = g * 16 + l16;
                bf16x8 wh = *(const bf16x8*)(lb + 16384 + wrow * 64 + kb);
                bf16x8 wl = *(const bf16x8*)(lb + 24576 + wrow * 64 + kb);
                acc[g] = MFMA16(ah, wh, acc[g], 0, 0, 0);
                acc[g] = MFMA16(ah, wl, acc[g], 0, 0, 0);
                acc[g] = MFMA16(al, wh, acc[g], 0, 0, 0);
            }
        } else {
            #pragma unroll
            for (int ks = 0; ks < 2; ++ks) {
                const int kb = ((ks * 64) + lq * 16) ^ swzA;
                bf16x8 ah = *(const bf16x8*)(lb + arow * 128 + kb);
                bf16x8 al = *(const bf16x8*)(lb + 8192 + arow * 128 + kb);
                #pragma unroll
                for (int g = 0; g < 4; ++g) {
                    const int wrow = g * 16 + l16;
                    bf16x8 wh = *(const bf16x8*)(lb + 16384 + wrow * 128 + kb);
                    bf16x8 wl = *(const bf16x8*)(lb + 24576 + wrow * 128 + kb);
                    acc[g] = MFMA16(ah, wh, acc[g], 0, 0, 0);
                    acc[g] = MFMA16(ah, wl, acc[g], 0, 0, 0);
                    acc[g] = MFMA16(al, wh, acc[g], 0, 0, 0);
                }
            }
        }

        // all my LDS reads have been consumed (lgkm waits before MFMAs);
        // belt-and-braces drain, then barrier so no wave still reads buf[i&1]
        asm volatile("s_waitcnt lgkmcnt(0)" ::: "memory");
        __builtin_amdgcn_s_barrier();
        if (i + 2 < NC) stageChunk(i + 2);        // overwrite buf[i&1]
    }

    // epilogue: C/D layout col=lane&15, row=(lane>>4)*4+reg -> 4 gates in-lane
    const int jj = j0 + l16;
    const float bi = A.bih[jj]          + A.bhh[jj];
    const float bf = A.bih[H_ + jj]     + A.bhh[H_ + jj];
    const float bg = A.bih[2 * H_ + jj] + A.bhh[2 * H_ + jj];
    const float bo = A.bih[3 * H_ + jj] + A.bhh[3 * H_ + jj];
    #pragma unroll
    for (int r = 0; r < 4; ++r) {
        const int  b    = row0 + wid * 16 + lq * 4 + r;
        const long base = (long)b * H_ + jj;
        const float cold = A.c[base];
        const float pi = acc[0][r] + bi, pf = acc[1][r] + bf;
        const float pg = acc[2][r] + bg, po = acc[3][r] + bo;
        const float cn = sig_(pf) * cold + sig_(pi) * tanhf(pg);
        const float hn = sig_(po) * tanhf(cn);
        A.c[base] = cn;
        const u16 hh = f2bf(hn);
        A.oh[base] = hh;
        A.ol[base] = f2bf(hn - bf2f(hh));
    }
}

// fp32 -> bf16 hi/lo split, 4 elements per thread
extern "C" __global__ void __launch_bounds__(256)
split4(const float* __restrict__ in, u16* __restrict__ hi, u16* __restrict__ lo, int n4)
{
    int i = blockIdx.x * 256 + threadIdx.x;
    if (i < n4) {
        float4 v = ((const float4*)in)[i];
        u16 h0 = f2bf(v.x), h1 = f2bf(v.y), h2 = f2bf(v.z), h3 = f2bf(v.w);
        ushort4 Hv; Hv.x = h0; Hv.y = h1; Hv.z = h2; Hv.w = h3;
        ushort4 Lv;
        Lv.x = f2bf(v.x - bf2f(h0)); Lv.y = f2bf(v.y - bf2f(h1));
        Lv.z = f2bf(v.z - bf2f(h2)); Lv.w = f2bf(v.w - bf2f(h3));
        ((ushort4*)hi)[i] = Hv; ((ushort4*)lo)[i] = Lv;
    }
}

extern "C" __global__ void __launch_bounds__(256)
zero16(uint4* p, int n)
{
    for (int i = blockIdx.x * 256 + threadIdx.x; i < n; i += gridDim.x * 256)
        p[i] = make_uint4(0, 0, 0, 0);
}

// mu / sigma heads for decoder step t ; h reconstructed as hi+lo
extern "C" __global__ void __launch_bounds__(256)
head_kernel(const u16* __restrict__ hh, const u16* __restrict__ hl,
            const float* __restrict__ W1, const float* __restrict__ b1,
            const float* __restrict__ W2, const float* __restrict__ b2,
            float* __restrict__ out, int t)
{
    int idx = blockIdx.x * 256 + threadIdx.x;          // 0..16383
    int b = idx >> 4, r = idx & 15, k = r & 7, which = r >> 3;
    const float* w  = (which ? W2 : W1) + (long)k * H_;
    const u16*   ph = hh + (long)b * H_;
    const u16*   pl = hl + (long)b * H_;
    float sum = 0.f;
    for (int d = 0; d < H_; d += 8) {
        uint4 uh = *(const uint4*)&ph[d];
        uint4 ul = *(const uint4*)&pl[d];
        float4 w0 = *(const float4*)&w[d];
        float4 w1 = *(const float4*)&w[d + 4];
        sum = fmaf(bf2f((u16)(uh.x & 0xffff)) + bf2f((u16)(ul.x & 0xffff)), w0.x, sum);
        sum = fmaf(bf2f((u16)(uh.x >> 16))    + bf2f((u16)(ul.x >> 16)),    w0.y, sum);
        sum = fmaf(bf2f((u16)(uh.y & 0xffff)) + bf2f((u16)(ul.y & 0xffff)), w0.z, sum);
        sum = fmaf(bf2f((u16)(uh.y >> 16))    + bf2f((u16)(ul.y >> 16)),    w0.w, sum);
        sum = fmaf(bf2f((u16)(uh.z & 0xffff)) + bf2f((u16)(ul.z & 0xffff)), w1.x, sum);
        sum = fmaf(bf2f((u16)(uh.z >> 16))    + bf2f((u16)(ul.z >> 16)),    w1.y, sum);
        sum = fmaf(bf2f((u16)(uh.w & 0xffff)) + bf2f((u16)(ul.w & 0xffff)), w1.z, sum);
        sum = fmaf(bf2f((u16)(uh.w >> 16))    + bf2f((u16)(ul.w >> 16)),    w1.w, sum);
    }
    long o = ((long)b * TAU_ + t) * K_ + k;
    if (which == 0) {
        out[o] = sum + b1[k];
    } else {
        float z  = 2.0f * (sum + b2[k]);
        float sp = fmaxf(z, 0.0f) + log1pf(expf(-fabsf(z)));
        out[(long)B_ * TAU_ * K_ + o] = 0.5f * sp;
    }
}

extern "C" void kernel_launch(void* const* d_in, const int* in_sizes, int n_in,
                              void* d_out, int out_size, void* d_ws, size_t ws_size,
                              hipStream_t stream)
{
    (void)in_sizes; (void)n_in; (void)out_size; (void)ws_size;

    const float* x     = (const float*)d_in[0];
    const float* eWih0 = (const float*)d_in[1];
    const float* eWhh0 = (const float*)d_in[2];
    const float* ebih0 = (const float*)d_in[3];
    const float* ebhh0 = (const float*)d_in[4];
    const float* eWih1 = (const float*)d_in[5];
    const float* eWhh1 = (const float*)d_in[6];
    const float* ebih1 = (const float*)d_in[7];
    const float* ebhh1 = (const float*)d_in[8];
    const float* dWih0 = (const float*)d_in[9];
    const float* dWhh0 = (const float*)d_in[10];
    const float* dbih0 = (const float*)d_in[11];
    const float* dbhh0 = (const float*)d_in[12];
    const float* dWih1 = (const float*)d_in[13];
    const float* dWhh1 = (const float*)d_in[14];
    const float* dbih1 = (const float*)d_in[15];
    const float* dbhh1 = (const float*)d_in[16];
    const float* W1    = (const float*)d_in[17];
    const float* b1    = (const float*)d_in[18];
    const float* W2    = (const float*)d_in[19];
    const float* b2    = (const float*)d_in[20];
    float* out = (float*)d_out;

    char* wsp = (char*)d_ws;
    auto take = [&](size_t n) { void* p = (void*)wsp; wsp += n; return p; };

    const size_t NX = (size_t)B_ * T_ * D_;
    u16* xh = (u16*)take(NX * 2);
    u16* xl = (u16*)take(NX * 2);

    const float* wsrc[8] = { eWih0, eWhh0, eWih1, eWhh1, dWih0, dWhh0, dWih1, dWhh1 };
    const size_t wn[8]   = { (size_t)2048 * 32, (size_t)2048 * 512, (size_t)2048 * 512,
                             (size_t)2048 * 512, (size_t)2048 * 512, (size_t)2048 * 512,
                             (size_t)2048 * 512, (size_t)2048 * 512 };
    u16 *wh[8], *wl[8];
    for (int i = 0; i < 8; ++i) { wh[i] = (u16*)take(wn[i] * 2); wl[i] = (u16*)take(wn[i] * 2); }

    const size_t NH = (size_t)B_ * H_;
    char* state0 = wsp;
    u16 *h0h[2], *h0l[2], *h1h[2], *h1l[2];
    for (int p = 0; p < 2; ++p) { h0h[p] = (u16*)take(NH * 2); h0l[p] = (u16*)take(NH * 2); }
    for (int p = 0; p < 2; ++p) { h1h[p] = (u16*)take(NH * 2); h1l[p] = (u16*)take(NH * 2); }
    float* c0 = (float*)take(NH * 4);
    float* c1 = (float*)take(NH * 4);
    const size_t stateBytes = (size_t)(wsp - state0);

    const dim3 blk(256);

    split4<<<dim3((unsigned)((NX / 4 + 255) / 256)), blk, 0, stream>>>(x, xh, xl, (int)(NX / 4));
    for (int i = 0; i < 8; ++i)
        split4<<<dim3((unsigned)((wn[i] / 4 + 255) / 256)), blk, 0, stream>>>(wsrc[i], wh[i], wl[i], (int)(wn[i] / 4));
    zero16<<<dim3(1024), blk, 0, stream>>>((uint4*)state0, (int)(stateBytes / 16));

    auto mkL0e = [&](int t, int pin, int pout) {
        CellA c;
        c.Ah = xh + (size_t)t * D_; c.Al = xl + (size_t)t * D_; c.lda = T_ * D_; c.Kx = D_;
        c.Wih_h = wh[0]; c.Wih_l = wl[0];
        c.Hh = h0h[pin]; c.Hl = h0l[pin];
        c.Whh_h = wh[1]; c.Whh_l = wl[1];
        c.bih = ebih0; c.bhh = ebhh0; c.c = c0;
        c.oh = h0h[pout]; c.ol = h0l[pout];
        return c;
    };
    auto mkL1e = [&](int pa, int pin, int pout) {
        CellA c;
        c.Ah = h0h[pa]; c.Al = h0l[pa]; c.lda = H_; c.Kx = H_;
        c.Wih_h = wh[2]; c.Wih_l = wl[2];
        c.Hh = h1h[pin]; c.Hl = h1l[pin];
        c.Whh_h = wh[3]; c.Whh_l = wl[3];
        c.bih = ebih1; c.bhh = ebhh1; c.c = c1;
        c.oh = h1h[pout]; c.ol = h1l[pout];
        return c;
    };
    auto mkL0d = [&](int pa, int pin, int pout) {
        CellA c;
        c.Ah = h1h[pa]; c.Al = h1l[pa]; c.lda = H_; c.Kx = H_;
        c.Wih_h = wh[4]; c.Wih_l = wl[4];
        c.Hh = h0h[pin]; c.Hl = h0l[pin];
        c.Whh_h = wh[5]; c.Whh_l = wl[5];
        c.bih = dbih0; c.bhh = dbhh0; c.c = c0;
        c.oh = h0h[pout]; c.ol = h0l[pout];
        return c;
    };
    auto mkL1d = [&](int pa, int pin, int pout) {
        CellA c;
        c.Ah = h0h[pa]; c.Al = h0l[pa]; c.lda = H_; c.Kx = H_;
        c.Wih_h = wh[6]; c.Wih_l = wl[6];
        c.Hh = h1h[pin]; c.Hl = h1l[pin];
        c.Whh_h = wh[7]; c.Whh_l = wl[7];
        c.bih = dbih1; c.bhh = dbhh1; c.c = c1;
        c.oh = h1h[pout]; c.ol = h1l[pout];
        return c;
    };

    int p0 = 1, p1 = 1;     // zeros live in buffer 1

    { CellA a = mkL0e(0, p0, p0 ^ 1);
      cell_kernel<<<dim3(512), blk, 0, stream>>>(a, a, 512); p0 ^= 1; }

    for (int t = 0; t < T_ - 1; ++t) {               // stagger: L1(t) || L0(t+1)
        CellA l1 = mkL1e(p0, p1, p1 ^ 1);
        CellA l0 = mkL0e(t + 1, p0, p0 ^ 1);
        cell_kernel<<<dim3(1024), blk, 0, stream>>>(l1, l0, 1024);
        p0 ^= 1; p1 ^= 1;
    }
    { CellA a = mkL1e(p0, p1, p1 ^ 1);
      cell_kernel<<<dim3(512), blk, 0, stream>>>(a, a, 512); p1 ^= 1; }

    for (int t = 0; t < TAU_; ++t) {
        CellA a = mkL0d(p1, p0, p0 ^ 1);
        cell_kernel<<<dim3(512), blk, 0, stream>>>(a, a, 512); p0 ^= 1;
        CellA b_ = mkL1d(p0, p1, p1 ^ 1);
        cell_kernel<<<dim3(512), blk, 0, stream>>>(b_, b_, 512); p1 ^= 1;
        head_kernel<<<dim3(64), blk, 0, stream>>>(h1h[p1], h1l[p1], W1, b1, W2, b2, out, t);
    }
}